// Round 5
// baseline (122.390 us; speedup 1.0000x reference)
//
#include <hip/hip_runtime.h>
#include <math.h>

#define N 1024
#define DIM 128
#define LAMB 0.9f
#define INV2SIG2 (1.0f / 450.0f)   // 0.5 / sigma^2, sigma=15

typedef short v8s __attribute__((ext_vector_type(8)));
typedef float v4f __attribute__((ext_vector_type(4)));
typedef unsigned int v4u __attribute__((ext_vector_type(4)));

__device__ __forceinline__ unsigned short f2bf(float x) {   // RNE float->bf16
    unsigned int u = __float_as_uint(x);
    u += 0x7FFFu + ((u >> 16) & 1u);
    return (unsigned short)(u >> 16);
}
__device__ __forceinline__ float bf2f(unsigned short h) {
    return __uint_as_float(((unsigned int)h) << 16);
}
__device__ __forceinline__ v8s cvt8(const float* p) {      // 8 fp32 -> v8s bf16
    v8s r;
    #pragma unroll
    for (int i = 0; i < 8; ++i) r[i] = (short)f2bf(p[i]);
    return r;
}

// Device-coherent (write-through to coherence point) stores: visible device-wide
// once vmcnt retires -> grid barrier needs no L2 wb/inv (verified round 3: -38us).
__device__ __forceinline__ void st_dc_f32(float* p, float v) {
    asm volatile("global_store_dword %0, %1, off sc0 sc1" :: "v"(p), "v"(v) : "memory");
}
__device__ __forceinline__ void st_dc_u16(unsigned short* p, unsigned short v) {
    unsigned int vv = v;
    asm volatile("global_store_short %0, %1, off sc0 sc1" :: "v"(p), "v"(vv) : "memory");
}
__device__ __forceinline__ void st_dc_b128(void* p, v4u v) {   // v4u: native vec,
    asm volatile("global_store_dwordx4 %0, %1, off sc0 sc1"    // uint4 struct is
                 :: "v"(p), "v"(v) : "memory");                // rejected by asm
}
__device__ __forceinline__ unsigned ld_far(const unsigned* p) {  // bypass caches
    unsigned r;
    asm volatile("global_load_dword %0, %1, off sc0 sc1\n\ts_waitcnt vmcnt(0)"
                 : "=v"(r) : "v"(p) : "memory");
    return r;
}

// Fence-free grid barrier, 8-way split arrival counters (64B apart) to kill
// same-line atomic serialization (round-3 residual). Wave 0 polls all 8 lines.
__device__ __forceinline__ void gridbar(unsigned* bars, unsigned tgt) {
    asm volatile("s_waitcnt vmcnt(0)" ::: "memory");   // dc stores drained
    __syncthreads();
    if (threadIdx.x < 64) {
        if (threadIdx.x == 0) atomicAdd(&bars[(blockIdx.x & 7) << 4], 1u);
        const unsigned* myc = &bars[(threadIdx.x & 7) << 4];
        while (true) {
            unsigned v = ld_far(myc);
            if (__all(v >= tgt)) break;
            __builtin_amdgcn_s_sleep(2);
        }
    }
    __syncthreads();
}

// ---- row dot: 64 lanes x 16 bf16 each vs fp32 z; returns full-wave sum ----
__device__ __forceinline__ float dot_row(uint4 ma, uint4 mb, const float* z, int lane) {
    const float4* z4 = (const float4*)(z + lane * 16);
    float4 z0 = z4[0], z1 = z4[1], z2 = z4[2], z3 = z4[3];
    float acc = 0.f;
    acc += bf2f((unsigned short)(ma.x)) * z0.x + bf2f((unsigned short)(ma.x >> 16)) * z0.y;
    acc += bf2f((unsigned short)(ma.y)) * z0.z + bf2f((unsigned short)(ma.y >> 16)) * z0.w;
    acc += bf2f((unsigned short)(ma.z)) * z1.x + bf2f((unsigned short)(ma.z >> 16)) * z1.y;
    acc += bf2f((unsigned short)(ma.w)) * z1.z + bf2f((unsigned short)(ma.w >> 16)) * z1.w;
    acc += bf2f((unsigned short)(mb.x)) * z2.x + bf2f((unsigned short)(mb.x >> 16)) * z2.y;
    acc += bf2f((unsigned short)(mb.y)) * z2.z + bf2f((unsigned short)(mb.y >> 16)) * z2.w;
    acc += bf2f((unsigned short)(mb.z)) * z3.x + bf2f((unsigned short)(mb.z >> 16)) * z3.y;
    acc += bf2f((unsigned short)(mb.w)) * z3.z + bf2f((unsigned short)(mb.w >> 16)) * z3.w;
    #pragma unroll
    for (int off = 32; off >= 1; off >>= 1) acc += __shfl_xor(acc, off, 64);
    return acc;
}

// ---------------- single fused kernel ----------------
__global__ __launch_bounds__(256) void k_mega(
    const float* __restrict__ f,
    const float* __restrict__ w1, const float* __restrict__ b1,
    const float* __restrict__ w2, const float* __restrict__ b2,
    const float* __restrict__ w3, const float* __restrict__ b3,
    const float* __restrict__ w4, const float* __restrict__ b4,
    float* __restrict__ ws, float* __restrict__ out)
{
    float* Wboth = ws;                                    // 32768
    float* bboth = ws + 32768;                            // 256
    float* fn2   = ws + 33024;                            // 1024 (in-kernel zeroed)
    float* mag   = ws + 34048;                            // 1024 (in-kernel zeroed)
    float* total = ws + 35072;                            // 1024 (in-kernel zeroed)
    unsigned* bars = (unsigned*)(ws + 36096);             // 8 ctrs, 64B apart
    unsigned* donecnt = bars + 128;
    float* A0  = ws + 36352;                              // 1024
    float* zb0 = ws + 37376;                              // 1024
    float* zb1 = ws + 38400;                              // 1024
    float* zb2 = ws + 39424;                              // 1024
    unsigned short* xb = (unsigned short*)(ws + 40448);   // 1024x128 bf16
    unsigned short* Bu = (unsigned short*)(ws + 105984);  // 1024x1024 bf16

    __shared__ __align__(16) float part[2][128];
    __shared__ __align__(16) float urow[128];
    __shared__ __align__(16) float bias_p[2][128];
    __shared__ __align__(16) float bias_v[128];
    __shared__ __align__(16) unsigned short Ctile[16][256];
    __shared__ float red4[4];
    __shared__ float bvalS;
    __shared__ __align__(16) float ush[1024];
    __shared__ int winner;

    const int b = blockIdx.x, t = threadIdx.x;
    const int wave = t >> 6, lane = t & 63;
    const int l15 = lane & 15, quad = lane >> 4;

    // -- prefetch this block's stage-B f rows into cache (hide HBM cold miss) --
    if (t < 128) {
        const float4* fp = (const float4*)(f + ((b >> 4) * 64 + (b & 15) * 4) * 128);
        float4 p0 = fp[t];
        asm volatile("" :: "v"(p0.x), "v"(p0.y), "v"(p0.z), "v"(p0.w));
    }
    // -- zero fn2/mag/total: 3072 floats = 256 blocks x 12 --
    if (t < 12) st_dc_f32(&fn2[b * 12 + t], 0.f);

    // ======== stage A: one composed-W row per block, K split across halves ======
    // X = W1*W4*W3*W2 (rows via chained vec-mats), G = W4*W3*W2.
    {
        const int j  = t & 127;
        const int kh = t >> 7;                 // K-half
        const int k0 = kh * 64;
        const float* rowp;
        const float* m1;
        if (b < 128) { rowp = w1 + b * 128; m1 = w4; }          // X row b
        else         { rowp = w4 + (b - 128) * 128; m1 = w3; }  // G row b-128
        float acc = 0.f;
        #pragma unroll 32
        for (int k = 0; k < 64; ++k) acc += rowp[k0 + k] * m1[(k0 + k) * 128 + j];
        part[kh][j] = acc;
        __syncthreads();
        if (t < 128) urow[t] = part[0][t] + part[1][t];
        __syncthreads();

        if (b < 128) {                       // X: extra middle hop through w3
            float a2 = 0.f;
            #pragma unroll 32
            for (int l = 0; l < 64; ++l) a2 += urow[k0 + l] * w3[(k0 + l) * 128 + j];
            part[kh][j] = a2;
            __syncthreads();
            if (t < 128) urow[t] = part[0][t] + part[1][t];
            __syncthreads();
        }
        float a3 = 0.f;
        #pragma unroll 32
        for (int l = 0; l < 64; ++l) a3 += urow[k0 + l] * w2[(k0 + l) * 128 + j];
        part[kh][j] = a3;
        __syncthreads();
        if (t < 128) {
            const int orow = (b < 128) ? (128 + b) : (b - 128);
            st_dc_f32(&Wboth[orow * 128 + t], part[0][t] + part[1][t]);
        }
    }
    if (b == 255) {                          // bias chain, float4 K-split
        const int i = t & 127, kh = t >> 7, k0 = kh * 64;
        const float4* bv4 = (const float4*)bias_v;
        {   const float4* wr = (const float4*)(w3 + i * 128 + k0);
            const float4* vr = (const float4*)(b2 + k0);
            float a = 0.f;
            #pragma unroll 16
            for (int q = 0; q < 16; ++q) {
                float4 x = wr[q], c = vr[q];
                a += x.x * c.x + x.y * c.y + x.z * c.z + x.w * c.w;
            }
            bias_p[kh][i] = a;
        }
        __syncthreads();
        if (t < 128) bias_v[t] = bias_p[0][t] + bias_p[1][t] + b3[t];
        __syncthreads();
        {   const float4* wr = (const float4*)(w4 + i * 128 + k0);
            float a = 0.f;
            #pragma unroll 16
            for (int q = 0; q < 16; ++q) {
                float4 x = wr[q], c = bv4[kh * 16 + q];
                a += x.x * c.x + x.y * c.y + x.z * c.z + x.w * c.w;
            }
            bias_p[kh][i] = a;
        }
        __syncthreads();
        if (t < 128) {
            float bg = bias_p[0][t] + bias_p[1][t] + b4[t];
            bias_v[t] = bg;
            st_dc_f32(&bboth[t], bg);
        }
        __syncthreads();
        {   const float4* wr = (const float4*)(w1 + i * 128 + k0);
            float a = 0.f;
            #pragma unroll 16
            for (int q = 0; q < 16; ++q) {
                float4 x = wr[q], c = bv4[kh * 16 + q];
                a += x.x * c.x + x.y * c.y + x.z * c.z + x.w * c.w;
            }
            bias_p[kh][i] = a;
        }
        __syncthreads();
        if (t < 128) st_dc_f32(&bboth[128 + t], bias_p[0][t] + bias_p[1][t] + b1[t]);
    }
    gridbar(bars, 32);

    // ======== stage B: Y = f @ Wb^T + bboth -> xb (bf16), fn2, mag ========
    {
        const int i0 = (b >> 4) * 64;
        const int j0 = (b & 15) * 16;
        const int ri = i0 + wave * 16;
        const float* ap = f     + (ri + l15) * 128 + quad * 8;
        const float* bp = Wboth + (j0 + l15) * 128 + quad * 8;
        v4f acc = {0.f, 0.f, 0.f, 0.f};
        #pragma unroll
        for (int kc = 0; kc < 4; ++kc) {
            v8s a   = cvt8(ap + kc * 32);
            v8s bbv = cvt8(bp + kc * 32);
            acc = __builtin_amdgcn_mfma_f32_16x16x32_bf16(a, bbv, acc, 0, 0, 0);
        }
        const float bias = bboth[j0 + l15];
        const bool isx = (j0 >= 128);
        float sq[4];
        #pragma unroll
        for (int reg = 0; reg < 4; ++reg) {
            float yv = acc[reg] + bias;
            sq[reg] = yv * yv;
            if (isx) st_dc_u16(&xb[(ri + quad * 4 + reg) * DIM + (j0 - 128) + l15],
                               f2bf(yv));
        }
        #pragma unroll
        for (int reg = 0; reg < 4; ++reg) {
            float ss = sq[reg];
            ss += __shfl_xor(ss, 1, 64); ss += __shfl_xor(ss, 2, 64);
            ss += __shfl_xor(ss, 4, 64); ss += __shfl_xor(ss, 8, 64);
            if (l15 == 0)
                atomicAdd((isx ? mag : fn2) + (ri + quad * 4 + reg), ss);
        }
    }
    gridbar(bars, 64);

    // ======== stage C: affinity -> Bu via LDS tile (coalesced 16B dc-flush) ====
    {
        const int slab = b >> 2;
        const int qtr  = b & 3;
        const int i0 = slab * 16;

        const unsigned short* ap = xb + (i0 + l15) * DIM + quad * 8;
        v8s afr[4];
        #pragma unroll
        for (int kc = 0; kc < 4; ++kc) afr[kc] = *(const v8s*)(ap + kc * 32);

        float rowsum[4] = {0.f, 0.f, 0.f, 0.f};
        #pragma unroll
        for (int s = 0; s < 4; ++s) {
            const int j0 = (qtr * 16 + wave * 4 + s) * 16;
            const unsigned short* bp = xb + (j0 + l15) * DIM + quad * 8;
            v4f acc = {0.f, 0.f, 0.f, 0.f};
            #pragma unroll
            for (int kc = 0; kc < 4; ++kc)
                acc = __builtin_amdgcn_mfma_f32_16x16x32_bf16(
                          afr[kc], *(const v8s*)(bp + kc * 32), acc, 0, 0, 0);
            const int gj = j0 + l15;
            const float rm = 1.0f / mag[gj];
            const float fj = fn2[gj] * INV2SIG2;
            #pragma unroll
            for (int reg = 0; reg < 4; ++reg) {
                const int gi = i0 + quad * 4 + reg;
                float Sv = acc[reg] * rm - 1.0f;
                float a = (gi == gj) ? 0.f : __expf(-(Sv * Sv) * fj);
                Ctile[quad * 4 + reg][(wave * 4 + s) * 16 + l15] = f2bf(a);
                rowsum[reg] += a;
                if (gi == 0) st_dc_f32(&A0[gj], a);
            }
        }
        #pragma unroll
        for (int reg = 0; reg < 4; ++reg) {
            float ss = rowsum[reg];
            ss += __shfl_xor(ss, 1, 64); ss += __shfl_xor(ss, 2, 64);
            ss += __shfl_xor(ss, 4, 64); ss += __shfl_xor(ss, 8, 64);
            if (l15 == 0) atomicAdd(&total[i0 + quad * 4 + reg], ss);
        }
        __syncthreads();
        const v4u* cs = (const v4u*)Ctile;
        #pragma unroll
        for (int p = 0; p < 2; ++p) {
            const int idx = p * 256 + t;      // 16B chunk index, 32 per row
            const int row = idx >> 5, chunk = idx & 31;
            st_dc_b128(Bu + (i0 + row) * N + qtr * 256 + chunk * 8, cs[idx]);
        }
    }
    gridbar(bars, 96);

    // ======== stages D/E/F: Neumann chain; Bu row cached in regs across iters ===
    {
        const int r = b * 4 + wave;
        const float r0s = 1.0f / fmaxf(total[0], 1e-10f);
        const float rscale = (r == 0) ? 0.f : LAMB / fmaxf(total[r], 1e-10f);
        const float p0r    = (r == 0) ? 0.f : A0[r] * r0s;
        const uint4* m4 = (const uint4*)(Bu + r * N + lane * 16);
        uint4 ma = m4[0], mb = m4[1];

        float d = dot_row(ma, mb, A0, lane);
        if (lane == 0) st_dc_f32(&zb0[r], p0r + rscale * r0s * d);
        gridbar(bars, 128);
        d = dot_row(ma, mb, zb0, lane);
        if (lane == 0) st_dc_f32(&zb1[r], p0r + rscale * d);
        gridbar(bars, 160);
        d = dot_row(ma, mb, zb1, lane);
        if (lane == 0) st_dc_f32(&zb2[r], p0r + rscale * d);
    }

    // last-block-done: fence-free (dc stores + vmcnt drain)
    asm volatile("s_waitcnt vmcnt(0)" ::: "memory");
    __syncthreads();
    if (t == 0) {
        unsigned int old = atomicAdd(donecnt, 1u);
        winner = (old == 255u) ? 1 : 0;
    }
    __syncthreads();
    if (!winner) return;

    // ---- 256-thread Aitken + softmax epilogue (zb2/zb1/zb0) ----
    const float* zM  = zb2;
    const float* zM1 = zb1;
    const float* zM2 = zb0;
    float av[4], d1v[4];
    float s12 = 0.f, s22 = 0.f;
    #pragma unroll
    for (int k = 0; k < 4; ++k) {
        const int e = t + 256 * k;
        av[k] = zM[e];
        float bb = zM1[e], cc = zM2[e];
        d1v[k] = av[k] - bb;
        float d2 = bb - cc;
        s12 += d1v[k] * d2;
        s22 += d2 * d2;
    }
    #pragma unroll
    for (int off = 32; off >= 1; off >>= 1) s12 += __shfl_down(s12, off, 64);
    if (lane == 0) red4[wave] = s12;
    __syncthreads();
    if (t == 0) bvalS = red4[0] + red4[1] + red4[2] + red4[3];
    __syncthreads();
    const float dot12 = bvalS;
    __syncthreads();
    #pragma unroll
    for (int off = 32; off >= 1; off >>= 1) s22 += __shfl_down(s22, off, 64);
    if (lane == 0) red4[wave] = s22;
    __syncthreads();
    if (t == 0) bvalS = red4[0] + red4[1] + red4[2] + red4[3];
    __syncthreads();
    const float dot22 = bvalS;
    __syncthreads();

    float lam = dot12 / fmaxf(dot22, 1e-30f);
    lam = fminf(fmaxf(lam, 0.0f), 0.95f);
    const float coef = lam / (1.0f - lam);
    #pragma unroll
    for (int k = 0; k < 4; ++k) ush[t + 256 * k] = av[k] + coef * d1v[k];
    __syncthreads();

    float Pv[4];
    float ps = 0.f;
    #pragma unroll
    for (int k = 0; k < 4; ++k) {
        const int e = t + 256 * k;
        Pv[k] = (e >= 1) ? 0.1f * ush[e] : 0.f;
        ps += Pv[k];
    }
    #pragma unroll
    for (int off = 32; off >= 1; off >>= 1) ps += __shfl_down(ps, off, 64);
    if (lane == 0) red4[wave] = ps;
    __syncthreads();
    if (t == 0) bvalS = (red4[0] + red4[1] + red4[2] + red4[3]) / 1023.0f;
    __syncthreads();
    const float mean = bvalS;
    __syncthreads();

    float mx = 0.f;
    #pragma unroll
    for (int k = 0; k < 4; ++k) {
        const int e = t + 256 * k;
        if (e >= 1) {
            Pv[k] = fmaxf(Pv[k] - mean, 0.f) * 100.f;
            mx = fmaxf(mx, Pv[k]);
        }
    }
    #pragma unroll
    for (int off = 32; off >= 1; off >>= 1) mx = fmaxf(mx, __shfl_down(mx, off, 64));
    if (lane == 0) red4[wave] = mx;
    __syncthreads();
    if (t == 0) bvalS = fmaxf(fmaxf(red4[0], red4[1]), fmaxf(red4[2], red4[3]));
    __syncthreads();
    const float gmax = bvalS;
    __syncthreads();

    float Ev[4];
    float es = 0.f;
    #pragma unroll
    for (int k = 0; k < 4; ++k) {
        const int e = t + 256 * k;
        Ev[k] = (e >= 1) ? expf(Pv[k] - gmax) : 0.f;
        es += Ev[k];
    }
    #pragma unroll
    for (int off = 32; off >= 1; off >>= 1) es += __shfl_down(es, off, 64);
    if (lane == 0) red4[wave] = es;
    __syncthreads();
    if (t == 0) bvalS = red4[0] + red4[1] + red4[2] + red4[3];
    __syncthreads();
    const float esum = bvalS;
    #pragma unroll
    for (int k = 0; k < 4; ++k) {
        const int e = t + 256 * k;
        if (e >= 1) out[e - 1] = Ev[k] / esum;
    }
}

extern "C" void kernel_launch(void* const* d_in, const int* in_sizes, int n_in,
                              void* d_out, int out_size, void* d_ws, size_t ws_size,
                              hipStream_t stream) {
    const float* f  = (const float*)d_in[0];
    const float* w1 = (const float*)d_in[1];
    const float* b1 = (const float*)d_in[2];
    const float* w2 = (const float*)d_in[3];
    const float* b2 = (const float*)d_in[4];
    const float* w3 = (const float*)d_in[5];
    const float* b3 = (const float*)d_in[6];
    const float* w4 = (const float*)d_in[7];
    const float* b4 = (const float*)d_in[8];
    float* ws = (float*)d_ws;

    // Zero the 8 split barrier counters + donecnt (cannot self-zero across graph
    // replays; workspace is re-poisoned each iteration).
    (void)hipMemsetAsync((char*)d_ws + 36096 * 4, 0, 576, stream);

    k_mega<<<256, 256, 0, stream>>>(f, w1, b1, w2, b2, w3, b3, w4, b4,
                                    ws, (float*)d_out);
}

// Round 6
// 118.396 us; speedup vs baseline: 1.0337x; 1.0337x over previous
//
#include <hip/hip_runtime.h>
#include <math.h>

#define N 1024
#define NM1 1023
#define DIM 128
#define LAMB 0.9f
#define INV2SIG2 (1.0f / 450.0f)   // 0.5 / sigma^2, sigma=15

typedef short v8s __attribute__((ext_vector_type(8)));
typedef float v4f __attribute__((ext_vector_type(4)));

__device__ __forceinline__ unsigned short f2bf(float x) {   // RNE float->bf16
    unsigned int u = __float_as_uint(x);
    u += 0x7FFFu + ((u >> 16) & 1u);
    return (unsigned short)(u >> 16);
}
__device__ __forceinline__ float bf2f(unsigned short h) {
    return __uint_as_float(((unsigned int)h) << 16);
}
__device__ __forceinline__ v8s cvt8(const float* p) {      // 8 fp32 -> v8s bf16
    v8s r;
    #pragma unroll
    for (int i = 0; i < 8; ++i) r[i] = (short)f2bf(p[i]);
    return r;
}

// ---------------- K0: compose. One output row per block (blocks 0..255), K split
// across thread-halves (2 latency chains/hop instead of ~16 — rounds 3-5 lesson).
// Block 256: bias chain (float4). Blocks 257..269: zero fn2/mag/total/donecnt.
// X = W1*W4*W3*W2 rows -> Wboth[128+b]; G = W4*W3*W2 rows -> Wboth[b-128].
__global__ __launch_bounds__(256) void k_compose(
    const float* __restrict__ w1, const float* __restrict__ w2,
    const float* __restrict__ w3, const float* __restrict__ w4,
    const float* __restrict__ b1, const float* __restrict__ b2,
    const float* __restrict__ b3, const float* __restrict__ b4,
    float* __restrict__ Wboth, float* __restrict__ bboth,
    float* __restrict__ zeros)   // fn2/mag/total/donecnt contiguous, 3328 floats
{
    __shared__ __align__(16) float part[2][128];
    __shared__ __align__(16) float urow[128];
    __shared__ __align__(16) float bias_v[128];
    const int b = blockIdx.x, t = threadIdx.x;
    const int j  = t & 127;
    const int kh = t >> 7;                 // K-half
    const int k0 = kh * 64;

    if (b < 256) {
        const float* rowp;
        const float* m1;
        if (b < 128) { rowp = w1 + b * 128; m1 = w4; }          // X row b
        else         { rowp = w4 + (b - 128) * 128; m1 = w3; }  // G row b-128
        float acc = 0.f;
        #pragma unroll 32
        for (int k = 0; k < 64; ++k) acc += rowp[k0 + k] * m1[(k0 + k) * 128 + j];
        part[kh][j] = acc;
        __syncthreads();
        if (t < 128) urow[t] = part[0][t] + part[1][t];
        __syncthreads();

        if (b < 128) {                       // X: extra middle hop through w3
            float a2 = 0.f;
            #pragma unroll 32
            for (int l = 0; l < 64; ++l) a2 += urow[k0 + l] * w3[(k0 + l) * 128 + j];
            part[kh][j] = a2;
            __syncthreads();
            if (t < 128) urow[t] = part[0][t] + part[1][t];
            __syncthreads();
        }
        float a3 = 0.f;
        #pragma unroll 32
        for (int l = 0; l < 64; ++l) a3 += urow[k0 + l] * w2[(k0 + l) * 128 + j];
        part[kh][j] = a3;
        __syncthreads();
        if (t < 128) {
            const int orow = (b < 128) ? (128 + b) : (b - 128);
            Wboth[orow * 128 + t] = part[0][t] + part[1][t];
        }
    } else if (b == 256) {                   // bias chain, float4 K-split
        const int i = j;
        const float4* bv4 = (const float4*)bias_v;
        {   const float4* wr = (const float4*)(w3 + i * 128 + k0);
            const float4* vr = (const float4*)(b2 + k0);
            float a = 0.f;
            #pragma unroll 16
            for (int q = 0; q < 16; ++q) {
                float4 x = wr[q], c = vr[q];
                a += x.x * c.x + x.y * c.y + x.z * c.z + x.w * c.w;
            }
            part[kh][i] = a;
        }
        __syncthreads();
        if (t < 128) bias_v[t] = part[0][t] + part[1][t] + b3[t];
        __syncthreads();
        {   const float4* wr = (const float4*)(w4 + i * 128 + k0);
            float a = 0.f;
            #pragma unroll 16
            for (int q = 0; q < 16; ++q) {
                float4 x = wr[q], c = bv4[kh * 16 + q];
                a += x.x * c.x + x.y * c.y + x.z * c.z + x.w * c.w;
            }
            part[kh][i] = a;
        }
        __syncthreads();
        if (t < 128) {
            float bg = part[0][t] + part[1][t] + b4[t];
            urow[t] = bg;
            bboth[t] = bg;                   // bg
        }
        __syncthreads();
        {   const float4* uv4 = (const float4*)urow;
            const float4* wr = (const float4*)(w1 + i * 128 + k0);
            float a = 0.f;
            #pragma unroll 16
            for (int q = 0; q < 16; ++q) {
                float4 x = wr[q], c = uv4[kh * 16 + q];
                a += x.x * c.x + x.y * c.y + x.z * c.z + x.w * c.w;
            }
            part[kh][i] = a;
        }
        __syncthreads();
        if (t < 128) bboth[128 + t] = part[0][t] + part[1][t] + b1[t];  // bx
    } else {                                 // zero 3328 floats (13 blocks)
        zeros[(b - 257) * 256 + t] = 0.f;
    }
}

// ---------------- K1: 256-block MFMA gemm Y = f @ Wb^T + bboth; xb, fn2, mag --------
__global__ __launch_bounds__(256) void k_gemm2(
    const float* __restrict__ f, const float* __restrict__ Wb,
    const float* __restrict__ bb,
    unsigned short* __restrict__ xb, float* __restrict__ fn2, float* __restrict__ mag)
{
    const int b = blockIdx.x, t = threadIdx.x;
    const int wave = t >> 6, lane = t & 63;
    const int l15 = lane & 15, quad = lane >> 4;
    const int i0 = (b >> 4) * 64;       // 16 row-tiles of 64
    const int j0 = (b & 15) * 16;       // 16 col-tiles of 16 (over 256 outputs)
    const int ri = i0 + wave * 16;
    const float* ap = f  + (ri + l15) * 128 + quad * 8;
    const float* bp = Wb + (j0 + l15) * 128 + quad * 8;
    v4f acc = {0.f, 0.f, 0.f, 0.f};
    #pragma unroll
    for (int kc = 0; kc < 4; ++kc) {
        v8s a   = cvt8(ap + kc * 32);
        v8s bbv = cvt8(bp + kc * 32);
        acc = __builtin_amdgcn_mfma_f32_16x16x32_bf16(a, bbv, acc, 0, 0, 0);
    }
    const float bias = bb[j0 + l15];
    const bool isx = (j0 >= 128);
    float sq[4];
    #pragma unroll
    for (int reg = 0; reg < 4; ++reg) {
        float yv = acc[reg] + bias;
        sq[reg] = yv * yv;
        if (isx) xb[(ri + quad * 4 + reg) * DIM + (j0 - 128) + l15] = f2bf(yv);
    }
    #pragma unroll
    for (int reg = 0; reg < 4; ++reg) {
        float ss = sq[reg];
        ss += __shfl_xor(ss, 1, 64); ss += __shfl_xor(ss, 2, 64);
        ss += __shfl_xor(ss, 4, 64); ss += __shfl_xor(ss, 8, 64);
        if (l15 == 0)
            atomicAdd((isx ? mag : fn2) + (ri + quad * 4 + reg), ss);
    }
}

// ---------------- K2: 256-block affinity -> Bu (UNSCALED bf16), totals, A0 ----------
__global__ __launch_bounds__(256) void k_aff(
    const unsigned short* __restrict__ xb, const float* __restrict__ mag,
    const float* __restrict__ fn2,
    unsigned short* __restrict__ Bu, float* __restrict__ A0,
    float* __restrict__ total)
{
    const int b = blockIdx.x, t = threadIdx.x;
    const int wave = t >> 6, lane = t & 63;
    const int l15 = lane & 15, quad = lane >> 4;
    const int slab = b >> 2;            // rows slab*16..+16
    const int qtr  = b & 3;             // j-quarter (256 cols)
    const int i0 = slab * 16;

    const unsigned short* ap = xb + (i0 + l15) * DIM + quad * 8;
    v8s afr[4];
    #pragma unroll
    for (int kc = 0; kc < 4; ++kc) afr[kc] = *(const v8s*)(ap + kc * 32);

    float rowsum[4] = {0.f, 0.f, 0.f, 0.f};
    #pragma unroll
    for (int s = 0; s < 4; ++s) {
        const int j0 = (qtr * 16 + wave * 4 + s) * 16;
        const unsigned short* bp = xb + (j0 + l15) * DIM + quad * 8;
        v4f acc = {0.f, 0.f, 0.f, 0.f};
        #pragma unroll
        for (int kc = 0; kc < 4; ++kc)
            acc = __builtin_amdgcn_mfma_f32_16x16x32_bf16(
                      afr[kc], *(const v8s*)(bp + kc * 32), acc, 0, 0, 0);
        const int gj = j0 + l15;
        const float rm = 1.0f / mag[gj];
        const float fj = fn2[gj] * INV2SIG2;
        #pragma unroll
        for (int reg = 0; reg < 4; ++reg) {
            const int gi = i0 + quad * 4 + reg;
            float Sv = acc[reg] * rm - 1.0f;
            float a = (gi == gj) ? 0.f : __expf(-(Sv * Sv) * fj);
            Bu[gi * N + gj] = f2bf(a);
            rowsum[reg] += a;
            if (gi == 0) A0[gj] = a;    // fp32 row 0 for P0
        }
    }
    #pragma unroll
    for (int reg = 0; reg < 4; ++reg) {
        float ss = rowsum[reg];
        ss += __shfl_xor(ss, 1, 64); ss += __shfl_xor(ss, 2, 64);
        ss += __shfl_xor(ss, 4, 64); ss += __shfl_xor(ss, 8, 64);
        if (l15 == 0) atomicAdd(&total[i0 + quad * 4 + reg], ss);
    }
}

// ---------------- K5: v[r] = P0[r] + rscale*(Bu z)[r]; last launch fuses the
//                  Aitken+softmax epilogue in the last-arriving block ----------
__global__ __launch_bounds__(256) void k_mvb2(
    const unsigned short* __restrict__ M, const float* __restrict__ A0,
    const float* __restrict__ total,
    const float* __restrict__ z, float* __restrict__ v, int first,
    int fin, const float* __restrict__ zM1, const float* __restrict__ zM2,
    unsigned int* donecnt, float* __restrict__ out)
{
    __shared__ float red4[4];
    __shared__ float bvalS;
    __shared__ float ush[1024];
    __shared__ int winner;
    const int t = threadIdx.x;
    const int wave = t >> 6, lane = t & 63;
    const int r = blockIdx.x * 4 + wave;
    const float r0s = 1.0f / fmaxf(total[0], 1e-10f);
    const float rscale = (r == 0) ? 0.f : LAMB / fmaxf(total[r], 1e-10f);
    const float p0r    = (r == 0) ? 0.f : A0[r] * r0s;
    const float zscale = first ? r0s : 1.0f;

    const uint4* m4 = (const uint4*)(M + r * N + lane * 16);
    const float4* z4 = (const float4*)(z + lane * 16);
    uint4 ma = m4[0], mb = m4[1];
    float4 z0 = z4[0], z1 = z4[1], z2 = z4[2], z3 = z4[3];
    float acc = 0.f;
    acc += bf2f((unsigned short)(ma.x)) * z0.x + bf2f((unsigned short)(ma.x >> 16)) * z0.y;
    acc += bf2f((unsigned short)(ma.y)) * z0.z + bf2f((unsigned short)(ma.y >> 16)) * z0.w;
    acc += bf2f((unsigned short)(ma.z)) * z1.x + bf2f((unsigned short)(ma.z >> 16)) * z1.y;
    acc += bf2f((unsigned short)(ma.w)) * z1.z + bf2f((unsigned short)(ma.w >> 16)) * z1.w;
    acc += bf2f((unsigned short)(mb.x)) * z2.x + bf2f((unsigned short)(mb.x >> 16)) * z2.y;
    acc += bf2f((unsigned short)(mb.y)) * z2.z + bf2f((unsigned short)(mb.y >> 16)) * z2.w;
    acc += bf2f((unsigned short)(mb.z)) * z3.x + bf2f((unsigned short)(mb.z >> 16)) * z3.y;
    acc += bf2f((unsigned short)(mb.w)) * z3.z + bf2f((unsigned short)(mb.w >> 16)) * z3.w;
    #pragma unroll
    for (int off = 32; off >= 1; off >>= 1) acc += __shfl_xor(acc, off, 64);
    if (lane == 0) v[r] = p0r + rscale * zscale * acc;

    if (!fin) return;
    // last-block-done: one release RMW per block (NOT a spin).
    __syncthreads();
    if (t == 0) {
        __threadfence();
        unsigned int old = atomicAdd(donecnt, 1u);
        winner = (old == 255u) ? 1 : 0;
        if (winner) __threadfence();
    }
    __syncthreads();
    if (!winner) return;

    // ---- 256-thread epilogue: zM = v ----
    const float* zM = v;
    float av[4], d1v[4];
    float s12 = 0.f, s22 = 0.f;
    #pragma unroll
    for (int k = 0; k < 4; ++k) {
        const int e = t + 256 * k;
        av[k] = zM[e];
        float bb = zM1[e], cc = zM2[e];
        d1v[k] = av[k] - bb;
        float d2 = bb - cc;
        s12 += d1v[k] * d2;
        s22 += d2 * d2;
    }
    #pragma unroll
    for (int off = 32; off >= 1; off >>= 1) s12 += __shfl_down(s12, off, 64);
    if (lane == 0) red4[wave] = s12;
    __syncthreads();
    if (t == 0) bvalS = red4[0] + red4[1] + red4[2] + red4[3];
    __syncthreads();
    const float dot12 = bvalS;
    __syncthreads();
    #pragma unroll
    for (int off = 32; off >= 1; off >>= 1) s22 += __shfl_down(s22, off, 64);
    if (lane == 0) red4[wave] = s22;
    __syncthreads();
    if (t == 0) bvalS = red4[0] + red4[1] + red4[2] + red4[3];
    __syncthreads();
    const float dot22 = bvalS;
    __syncthreads();

    float lam = dot12 / fmaxf(dot22, 1e-30f);
    lam = fminf(fmaxf(lam, 0.0f), 0.95f);
    const float coef = lam / (1.0f - lam);
    #pragma unroll
    for (int k = 0; k < 4; ++k) ush[t + 256 * k] = av[k] + coef * d1v[k];
    __syncthreads();

    float Pv[4];
    float ps = 0.f;
    #pragma unroll
    for (int k = 0; k < 4; ++k) {
        const int e = t + 256 * k;
        Pv[k] = (e >= 1) ? 0.1f * ush[e] : 0.f;
        ps += Pv[k];
    }
    #pragma unroll
    for (int off = 32; off >= 1; off >>= 1) ps += __shfl_down(ps, off, 64);
    if (lane == 0) red4[wave] = ps;
    __syncthreads();
    if (t == 0) bvalS = (red4[0] + red4[1] + red4[2] + red4[3]) / 1023.0f;
    __syncthreads();
    const float mean = bvalS;
    __syncthreads();

    float mx = 0.f;   // relu'd values >= 0
    #pragma unroll
    for (int k = 0; k < 4; ++k) {
        const int e = t + 256 * k;
        if (e >= 1) {
            Pv[k] = fmaxf(Pv[k] - mean, 0.f) * 100.f;
            mx = fmaxf(mx, Pv[k]);
        }
    }
    #pragma unroll
    for (int off = 32; off >= 1; off >>= 1) mx = fmaxf(mx, __shfl_down(mx, off, 64));
    if (lane == 0) red4[wave] = mx;
    __syncthreads();
    if (t == 0) bvalS = fmaxf(fmaxf(red4[0], red4[1]), fmaxf(red4[2], red4[3]));
    __syncthreads();
    const float gmax = bvalS;
    __syncthreads();

    float Ev[4];
    float es = 0.f;
    #pragma unroll
    for (int k = 0; k < 4; ++k) {
        const int e = t + 256 * k;
        Ev[k] = (e >= 1) ? expf(Pv[k] - gmax) : 0.f;
        es += Ev[k];
    }
    #pragma unroll
    for (int off = 32; off >= 1; off >>= 1) es += __shfl_down(es, off, 64);
    if (lane == 0) red4[wave] = es;
    __syncthreads();
    if (t == 0) bvalS = red4[0] + red4[1] + red4[2] + red4[3];
    __syncthreads();
    const float esum = bvalS;
    #pragma unroll
    for (int k = 0; k < 4; ++k) {
        const int e = t + 256 * k;
        if (e >= 1) out[e - 1] = Ev[k] / esum;
    }
}

extern "C" void kernel_launch(void* const* d_in, const int* in_sizes, int n_in,
                              void* d_out, int out_size, void* d_ws, size_t ws_size,
                              hipStream_t stream) {
    const float* f  = (const float*)d_in[0];
    const float* w1 = (const float*)d_in[1];
    const float* b1 = (const float*)d_in[2];
    const float* w2 = (const float*)d_in[3];
    const float* b2 = (const float*)d_in[4];
    const float* w3 = (const float*)d_in[5];
    const float* b3 = (const float*)d_in[6];
    const float* w4 = (const float*)d_in[7];
    const float* b4 = (const float*)d_in[8];
    float* ws = (float*)d_ws;

    // float-unit offsets
    float* Wboth = ws;                                   // 32768
    float* bboth = ws + 32768;                           // 256
    float* fn2   = ws + 33024;                           // 1024  (fn2/mag/total/donecnt
    float* mag   = ws + 34048;                           //  contiguous, zeroed together)
    float* total = ws + 35072;                           // 1024
    unsigned int* donecnt = (unsigned int*)(ws + 36096); // 256-float pad
    float* A0    = ws + 36352;                           // 1024
    float* zb0   = ws + 37376;                           // 1024
    float* zb1   = ws + 38400;                           // 1024
    float* zb2   = ws + 39424;                           // 1024
    unsigned short* xb = (unsigned short*)(ws + 40448);  // 65536 floats
    unsigned short* Bu = (unsigned short*)(ws + 105984); // 524288 floats
    float* out = (float*)d_out;

    k_compose<<<270, 256, 0, stream>>>(w1, w2, w3, w4, b1, b2, b3, b4,
                                       Wboth, bboth, fn2);
    k_gemm2<<<256, 256, 0, stream>>>(f, Wboth, bboth, xb, fn2, mag);
    k_aff<<<256, 256, 0, stream>>>(xb, mag, fn2, Bu, A0, total);

    // Neumann chain, 3 steps; it0 consumes fp32 A0 with folded 1/total0;
    // it2 fuses the epilogue via last-block-done.
    k_mvb2<<<256, 256, 0, stream>>>(Bu, A0, total, A0,  zb0, 1, 0,
                                    nullptr, nullptr, donecnt, out);
    k_mvb2<<<256, 256, 0, stream>>>(Bu, A0, total, zb0, zb1, 0, 0,
                                    nullptr, nullptr, donecnt, out);
    k_mvb2<<<256, 256, 0, stream>>>(Bu, A0, total, zb1, zb2, 0, 1,
                                    zb1, zb0, donecnt, out);
}

// Round 7
// 105.933 us; speedup vs baseline: 1.1553x; 1.1176x over previous
//
#include <hip/hip_runtime.h>
#include <math.h>

#define N 1024
#define NM1 1023
#define DIM 128
#define LAMB 0.9f
#define INV2SIG2 (1.0f / 450.0f)   // 0.5 / sigma^2, sigma=15

typedef short v8s __attribute__((ext_vector_type(8)));
typedef float v4f __attribute__((ext_vector_type(4)));

__device__ __forceinline__ unsigned short f2bf(float x) {   // RNE float->bf16
    unsigned int u = __float_as_uint(x);
    u += 0x7FFFu + ((u >> 16) & 1u);
    return (unsigned short)(u >> 16);
}
__device__ __forceinline__ float bf2f(unsigned short h) {
    return __uint_as_float(((unsigned int)h) << 16);
}
__device__ __forceinline__ v8s cvt8(const float* p) {      // 8 fp32 -> v8s bf16
    v8s r;
    #pragma unroll
    for (int i = 0; i < 8; ++i) r[i] = (short)f2bf(p[i]);
    return r;
}

// Device-coherent store (write-through to coherence point): visible device-wide
// once vmcnt retires -> small-grid barrier needs no L2 wb/inv (round-3 verified).
__device__ __forceinline__ void st_dc_f32(float* p, float v) {
    asm volatile("global_store_dword %0, %1, off sc0 sc1" :: "v"(p), "v"(v) : "memory");
}

// Fence-free grid barrier for the SMALL (64-block) mv grid. Sync cost scales
// with block count (rounds 1-6 lesson: 256-block sync ~ 6us whether boundary or
// barrier); 64 arrivals + relaxed poll should be ~1-2us.
__device__ __forceinline__ void gridbar64(unsigned int* bar, unsigned int tgt) {
    asm volatile("s_waitcnt vmcnt(0)" ::: "memory");   // dc stores drained
    __syncthreads();
    if (threadIdx.x == 0) {
        atomicAdd(bar, 1u);
        unsigned int v;
        do {
            __builtin_amdgcn_s_sleep(1);
            v = __hip_atomic_load(bar, __ATOMIC_RELAXED, __HIP_MEMORY_SCOPE_AGENT);
        } while (v < tgt);
    }
    __syncthreads();
}

// ---------------- K0: fused compose (round-0 verified version) ----------
__global__ __launch_bounds__(256) void k_compose(
    const float* __restrict__ w1, const float* __restrict__ w2,
    const float* __restrict__ w3, const float* __restrict__ w4,
    const float* __restrict__ b1, const float* __restrict__ b2,
    const float* __restrict__ b3, const float* __restrict__ b4,
    float* __restrict__ Wboth, float* __restrict__ bboth,
    float* __restrict__ zeros)   // fn2/mag/total/donecnt/bar contiguous, 3328 floats
{
    __shared__ float u0[2][128];
    __shared__ float u1[2][128];
    const int b = blockIdx.x, t = threadIdx.x;
    const int h = t >> 7, j = t & 127;
    if (b < 64) {                       // G rows 2b, 2b+1
        const int i = 2 * b + h;
        float acc = 0.f;
        #pragma unroll 8
        for (int k = 0; k < 128; ++k) acc += w4[i * 128 + k] * w3[k * 128 + j];
        u0[h][j] = acc;
        __syncthreads();
        float acc2 = 0.f;
        #pragma unroll 8
        for (int l = 0; l < 128; ++l) acc2 += u0[h][l] * w2[l * 128 + j];
        Wboth[i * 128 + j] = acc2;
    } else if (b < 128) {               // X rows
        const int i = 2 * (b - 64) + h;
        float acc = 0.f;
        #pragma unroll 8
        for (int k = 0; k < 128; ++k) acc += w1[i * 128 + k] * w4[k * 128 + j];
        u0[h][j] = acc;
        __syncthreads();
        float acc2 = 0.f;
        #pragma unroll 8
        for (int k = 0; k < 128; ++k) acc2 += u0[h][k] * w3[k * 128 + j];
        u1[h][j] = acc2;
        __syncthreads();
        float acc3 = 0.f;
        #pragma unroll 8
        for (int l = 0; l < 128; ++l) acc3 += u1[h][l] * w2[l * 128 + j];
        Wboth[(128 + i) * 128 + j] = acc3;
    } else if (b == 128) {              // bias chain (3 sequential vec-mats)
        if (t < 128) {
            float a3 = b3[t];
            #pragma unroll 8
            for (int k = 0; k < 128; ++k) a3 += w3[t * 128 + k] * b2[k];
            u0[0][t] = a3;
        }
        __syncthreads();
        if (t < 128) {
            float a4 = b4[t];
            #pragma unroll 8
            for (int k = 0; k < 128; ++k) a4 += w4[t * 128 + k] * u0[0][k];
            u1[0][t] = a4;
            bboth[t] = a4;              // bg
        }
        __syncthreads();
        if (t < 128) {
            float ax = b1[t];
            #pragma unroll 8
            for (int k = 0; k < 128; ++k) ax += w1[t * 128 + k] * u1[0][k];
            bboth[128 + t] = ax;        // bx
        }
    } else {                            // zero fn2/mag/total/donecnt/bar (3328 floats)
        #pragma unroll
        for (int s = 0; s < 13; ++s) zeros[t + 256 * s] = 0.f;
    }
}

// ---------------- K1: 256-block MFMA gemm Y = f @ Wb^T + bboth; xb, fn2, mag --------
__global__ __launch_bounds__(256) void k_gemm2(
    const float* __restrict__ f, const float* __restrict__ Wb,
    const float* __restrict__ bb,
    unsigned short* __restrict__ xb, float* __restrict__ fn2, float* __restrict__ mag)
{
    const int b = blockIdx.x, t = threadIdx.x;
    const int wave = t >> 6, lane = t & 63;
    const int l15 = lane & 15, quad = lane >> 4;
    const int i0 = (b >> 4) * 64;       // 16 row-tiles of 64
    const int j0 = (b & 15) * 16;       // 16 col-tiles of 16 (over 256 outputs)
    const int ri = i0 + wave * 16;
    const float* ap = f  + (ri + l15) * 128 + quad * 8;
    const float* bp = Wb + (j0 + l15) * 128 + quad * 8;
    v4f acc = {0.f, 0.f, 0.f, 0.f};
    #pragma unroll
    for (int kc = 0; kc < 4; ++kc) {
        v8s a   = cvt8(ap + kc * 32);
        v8s bbv = cvt8(bp + kc * 32);
        acc = __builtin_amdgcn_mfma_f32_16x16x32_bf16(a, bbv, acc, 0, 0, 0);
    }
    const float bias = bb[j0 + l15];
    const bool isx = (j0 >= 128);
    float sq[4];
    #pragma unroll
    for (int reg = 0; reg < 4; ++reg) {
        float yv = acc[reg] + bias;
        sq[reg] = yv * yv;
        if (isx) xb[(ri + quad * 4 + reg) * DIM + (j0 - 128) + l15] = f2bf(yv);
    }
    #pragma unroll
    for (int reg = 0; reg < 4; ++reg) {
        float ss = sq[reg];
        ss += __shfl_xor(ss, 1, 64); ss += __shfl_xor(ss, 2, 64);
        ss += __shfl_xor(ss, 4, 64); ss += __shfl_xor(ss, 8, 64);
        if (l15 == 0)
            atomicAdd((isx ? mag : fn2) + (ri + quad * 4 + reg), ss);
    }
}

// ---------------- K2: 256-block affinity -> Bu (UNSCALED bf16), totals, A0 ----------
__global__ __launch_bounds__(256) void k_aff(
    const unsigned short* __restrict__ xb, const float* __restrict__ mag,
    const float* __restrict__ fn2,
    unsigned short* __restrict__ Bu, float* __restrict__ A0,
    float* __restrict__ total)
{
    const int b = blockIdx.x, t = threadIdx.x;
    const int wave = t >> 6, lane = t & 63;
    const int l15 = lane & 15, quad = lane >> 4;
    const int slab = b >> 2;            // rows slab*16..+16
    const int qtr  = b & 3;             // j-quarter (256 cols)
    const int i0 = slab * 16;

    const unsigned short* ap = xb + (i0 + l15) * DIM + quad * 8;
    v8s afr[4];
    #pragma unroll
    for (int kc = 0; kc < 4; ++kc) afr[kc] = *(const v8s*)(ap + kc * 32);

    float rowsum[4] = {0.f, 0.f, 0.f, 0.f};
    #pragma unroll
    for (int s = 0; s < 4; ++s) {
        const int j0 = (qtr * 16 + wave * 4 + s) * 16;
        const unsigned short* bp = xb + (j0 + l15) * DIM + quad * 8;
        v4f acc = {0.f, 0.f, 0.f, 0.f};
        #pragma unroll
        for (int kc = 0; kc < 4; ++kc)
            acc = __builtin_amdgcn_mfma_f32_16x16x32_bf16(
                      afr[kc], *(const v8s*)(bp + kc * 32), acc, 0, 0, 0);
        const int gj = j0 + l15;
        const float rm = 1.0f / mag[gj];
        const float fj = fn2[gj] * INV2SIG2;
        #pragma unroll
        for (int reg = 0; reg < 4; ++reg) {
            const int gi = i0 + quad * 4 + reg;
            float Sv = acc[reg] * rm - 1.0f;
            float a = (gi == gj) ? 0.f : __expf(-(Sv * Sv) * fj);
            Bu[gi * N + gj] = f2bf(a);
            rowsum[reg] += a;
            if (gi == 0) A0[gj] = a;    // fp32 row 0 for P0
        }
    }
    #pragma unroll
    for (int reg = 0; reg < 4; ++reg) {
        float ss = rowsum[reg];
        ss += __shfl_xor(ss, 1, 64); ss += __shfl_xor(ss, 2, 64);
        ss += __shfl_xor(ss, 4, 64); ss += __shfl_xor(ss, 8, 64);
        if (l15 == 0) atomicAdd(&total[i0 + quad * 4 + reg], ss);
    }
}

// ---- partial dot for one cached Bu row against z held in registers ----
__device__ __forceinline__ float dotp(uint4 ma, uint4 mb,
                                      float4 z0, float4 z1, float4 z2, float4 z3) {
    float acc = 0.f;
    acc += bf2f((unsigned short)(ma.x)) * z0.x + bf2f((unsigned short)(ma.x >> 16)) * z0.y;
    acc += bf2f((unsigned short)(ma.y)) * z0.z + bf2f((unsigned short)(ma.y >> 16)) * z0.w;
    acc += bf2f((unsigned short)(ma.z)) * z1.x + bf2f((unsigned short)(ma.z >> 16)) * z1.y;
    acc += bf2f((unsigned short)(ma.w)) * z1.z + bf2f((unsigned short)(ma.w >> 16)) * z1.w;
    acc += bf2f((unsigned short)(mb.x)) * z2.x + bf2f((unsigned short)(mb.x >> 16)) * z2.y;
    acc += bf2f((unsigned short)(mb.y)) * z2.z + bf2f((unsigned short)(mb.y >> 16)) * z2.w;
    acc += bf2f((unsigned short)(mb.z)) * z3.x + bf2f((unsigned short)(mb.z >> 16)) * z3.y;
    acc += bf2f((unsigned short)(mb.w)) * z3.z + bf2f((unsigned short)(mb.w >> 16)) * z3.w;
    return acc;
}

// ---------------- K3: all 3 Neumann matvecs in ONE 64-block kernel + epilogue ----
// 16 rows/block (4/wave), Bu rows cached in registers across the 3 iterations;
// two cheap 64-block barriers replace two full 256-block kernel boundaries.
__global__ __launch_bounds__(256) void k_mv3(
    const unsigned short* __restrict__ M, const float* __restrict__ A0,
    const float* __restrict__ total,
    float* __restrict__ zb0, float* __restrict__ zb1, float* __restrict__ zb2,
    unsigned int* __restrict__ bar, unsigned int* __restrict__ donecnt,
    float* __restrict__ out)
{
    __shared__ float red4[4];
    __shared__ float bvalS;
    __shared__ float ush[1024];
    __shared__ int winner;
    const int b = blockIdx.x, t = threadIdx.x;
    const int wave = t >> 6, lane = t & 63;
    const int rbase = b * 16 + wave * 4;

    const float r0s = 1.0f / fmaxf(total[0], 1e-10f);
    uint4 ma[4], mb[4];
    float rsc[4], p0r[4];
    #pragma unroll
    for (int rr = 0; rr < 4; ++rr) {
        const int r = rbase + rr;
        const uint4* m4 = (const uint4*)(M + r * N + lane * 16);
        ma[rr] = m4[0]; mb[rr] = m4[1];
        rsc[rr] = (r == 0) ? 0.f : LAMB / fmaxf(total[r], 1e-10f);
        p0r[rr] = (r == 0) ? 0.f : A0[r] * r0s;
    }

    // ---- it0: z = A0 (zscale = r0s) -> zb0 ----
    {
        const float4* z4 = (const float4*)(A0 + lane * 16);
        float4 z0 = z4[0], z1 = z4[1], z2 = z4[2], z3 = z4[3];
        #pragma unroll
        for (int rr = 0; rr < 4; ++rr) {
            float acc = dotp(ma[rr], mb[rr], z0, z1, z2, z3);
            #pragma unroll
            for (int off = 32; off >= 1; off >>= 1) acc += __shfl_xor(acc, off, 64);
            if (lane == 0) st_dc_f32(&zb0[rbase + rr], p0r[rr] + rsc[rr] * r0s * acc);
        }
    }
    gridbar64(bar, 64);
    // ---- it1: z = zb0 -> zb1 ----
    {
        const float4* z4 = (const float4*)(zb0 + lane * 16);
        float4 z0 = z4[0], z1 = z4[1], z2 = z4[2], z3 = z4[3];
        #pragma unroll
        for (int rr = 0; rr < 4; ++rr) {
            float acc = dotp(ma[rr], mb[rr], z0, z1, z2, z3);
            #pragma unroll
            for (int off = 32; off >= 1; off >>= 1) acc += __shfl_xor(acc, off, 64);
            if (lane == 0) st_dc_f32(&zb1[rbase + rr], p0r[rr] + rsc[rr] * acc);
        }
    }
    gridbar64(bar, 128);
    // ---- it2: z = zb1 -> zb2 ----
    {
        const float4* z4 = (const float4*)(zb1 + lane * 16);
        float4 z0 = z4[0], z1 = z4[1], z2 = z4[2], z3 = z4[3];
        #pragma unroll
        for (int rr = 0; rr < 4; ++rr) {
            float acc = dotp(ma[rr], mb[rr], z0, z1, z2, z3);
            #pragma unroll
            for (int off = 32; off >= 1; off >>= 1) acc += __shfl_xor(acc, off, 64);
            if (lane == 0) st_dc_f32(&zb2[rbase + rr], p0r[rr] + rsc[rr] * acc);
        }
    }

    // last-block-done: fence-free (dc stores + vmcnt drain), 64 blocks
    asm volatile("s_waitcnt vmcnt(0)" ::: "memory");
    __syncthreads();
    if (t == 0) {
        unsigned int old = atomicAdd(donecnt, 1u);
        winner = (old == 63u) ? 1 : 0;
    }
    __syncthreads();
    if (!winner) return;

    // ---- 256-thread Aitken + softmax epilogue: zM=zb2, zM1=zb1, zM2=zb0 ----
    const float* zM  = zb2;
    const float* zM1 = zb1;
    const float* zM2 = zb0;
    float av[4], d1v[4];
    float s12 = 0.f, s22 = 0.f;
    #pragma unroll
    for (int k = 0; k < 4; ++k) {
        const int e = t + 256 * k;
        av[k] = zM[e];
        float bb = zM1[e], cc = zM2[e];
        d1v[k] = av[k] - bb;
        float d2 = bb - cc;
        s12 += d1v[k] * d2;
        s22 += d2 * d2;
    }
    #pragma unroll
    for (int off = 32; off >= 1; off >>= 1) s12 += __shfl_down(s12, off, 64);
    if (lane == 0) red4[wave] = s12;
    __syncthreads();
    if (t == 0) bvalS = red4[0] + red4[1] + red4[2] + red4[3];
    __syncthreads();
    const float dot12 = bvalS;
    __syncthreads();
    #pragma unroll
    for (int off = 32; off >= 1; off >>= 1) s22 += __shfl_down(s22, off, 64);
    if (lane == 0) red4[wave] = s22;
    __syncthreads();
    if (t == 0) bvalS = red4[0] + red4[1] + red4[2] + red4[3];
    __syncthreads();
    const float dot22 = bvalS;
    __syncthreads();

    float lam = dot12 / fmaxf(dot22, 1e-30f);
    lam = fminf(fmaxf(lam, 0.0f), 0.95f);
    const float coef = lam / (1.0f - lam);
    #pragma unroll
    for (int k = 0; k < 4; ++k) ush[t + 256 * k] = av[k] + coef * d1v[k];
    __syncthreads();

    float Pv[4];
    float ps = 0.f;
    #pragma unroll
    for (int k = 0; k < 4; ++k) {
        const int e = t + 256 * k;
        Pv[k] = (e >= 1) ? 0.1f * ush[e] : 0.f;
        ps += Pv[k];
    }
    #pragma unroll
    for (int off = 32; off >= 1; off >>= 1) ps += __shfl_down(ps, off, 64);
    if (lane == 0) red4[wave] = ps;
    __syncthreads();
    if (t == 0) bvalS = (red4[0] + red4[1] + red4[2] + red4[3]) / 1023.0f;
    __syncthreads();
    const float mean = bvalS;
    __syncthreads();

    float mx = 0.f;   // relu'd values >= 0
    #pragma unroll
    for (int k = 0; k < 4; ++k) {
        const int e = t + 256 * k;
        if (e >= 1) {
            Pv[k] = fmaxf(Pv[k] - mean, 0.f) * 100.f;
            mx = fmaxf(mx, Pv[k]);
        }
    }
    #pragma unroll
    for (int off = 32; off >= 1; off >>= 1) mx = fmaxf(mx, __shfl_down(mx, off, 64));
    if (lane == 0) red4[wave] = mx;
    __syncthreads();
    if (t == 0) bvalS = fmaxf(fmaxf(red4[0], red4[1]), fmaxf(red4[2], red4[3]));
    __syncthreads();
    const float gmax = bvalS;
    __syncthreads();

    float Ev[4];
    float es = 0.f;
    #pragma unroll
    for (int k = 0; k < 4; ++k) {
        const int e = t + 256 * k;
        Ev[k] = (e >= 1) ? expf(Pv[k] - gmax) : 0.f;
        es += Ev[k];
    }
    #pragma unroll
    for (int off = 32; off >= 1; off >>= 1) es += __shfl_down(es, off, 64);
    if (lane == 0) red4[wave] = es;
    __syncthreads();
    if (t == 0) bvalS = red4[0] + red4[1] + red4[2] + red4[3];
    __syncthreads();
    const float esum = bvalS;
    #pragma unroll
    for (int k = 0; k < 4; ++k) {
        const int e = t + 256 * k;
        if (e >= 1) out[e - 1] = Ev[k] / esum;
    }
}

extern "C" void kernel_launch(void* const* d_in, const int* in_sizes, int n_in,
                              void* d_out, int out_size, void* d_ws, size_t ws_size,
                              hipStream_t stream) {
    const float* f  = (const float*)d_in[0];
    const float* w1 = (const float*)d_in[1];
    const float* b1 = (const float*)d_in[2];
    const float* w2 = (const float*)d_in[3];
    const float* b2 = (const float*)d_in[4];
    const float* w3 = (const float*)d_in[5];
    const float* b3 = (const float*)d_in[6];
    const float* w4 = (const float*)d_in[7];
    const float* b4 = (const float*)d_in[8];
    float* ws = (float*)d_ws;

    // float-unit offsets
    float* Wboth = ws;                                   // 32768
    float* bboth = ws + 32768;                           // 256
    float* fn2   = ws + 33024;                           // 1024  (fn2/mag/total/donecnt
    float* mag   = ws + 34048;                           //  /bar contiguous, zeroed
    float* total = ws + 35072;                           //  together in k_compose)
    unsigned int* donecnt = (unsigned int*)(ws + 36096);
    unsigned int* bar     = (unsigned int*)(ws + 36097);
    float* A0    = ws + 36352;                           // 1024
    float* zb0   = ws + 37376;                           // 1024
    float* zb1   = ws + 38400;                           // 1024
    float* zb2   = ws + 39424;                           // 1024
    unsigned short* xb = (unsigned short*)(ws + 40448);  // 65536 floats
    unsigned short* Bu = (unsigned short*)(ws + 105984); // 524288 floats
    float* out = (float*)d_out;

    k_compose<<<130, 256, 0, stream>>>(w1, w2, w3, w4, b1, b2, b3, b4,
                                       Wboth, bboth, fn2);
    k_gemm2<<<256, 256, 0, stream>>>(f, Wboth, bboth, xb, fn2, mag);
    k_aff<<<256, 256, 0, stream>>>(xb, mag, fn2, Bu, A0, total);
    k_mv3<<<64, 256, 0, stream>>>(Bu, A0, total, zb0, zb1, zb2,
                                  bar, donecnt, out);
}